// Round 2
// baseline (66485.168 us; speedup 1.0000x reference)
//
#include <hip/hip_runtime.h>
#include <hip/hip_bf16.h>
#include <hip/hip_cooperative_groups.h>

namespace cg = cooperative_groups;

#define BB 32
#define LL 2048
#define DD 127
#define HH 256
#define OM 128
#define NSTEP 2047

typedef short short8 __attribute__((ext_vector_type(8)));
typedef unsigned short u16x8 __attribute__((ext_vector_type(8)));
typedef float f32x4 __attribute__((ext_vector_type(4)));

__device__ __forceinline__ unsigned short f2bf(float f) {
    union { float f; unsigned int u; } v; v.f = f;
    unsigned int u = v.u;
    return (unsigned short)((u + 0x7fffu + ((u >> 16) & 1u)) >> 16);
}
__device__ __forceinline__ float bf2f(unsigned short b) {
    union { float f; unsigned int u; } v; v.u = ((unsigned int)b) << 16;
    return v.f;
}

// LDS layout (bytes): A_hi[128][256]bf16 | A_lo[128][256]bf16 | y_s[32][256]bf16 | vfB[128]f32 | red[4][2][16]f32
#define OFF_AHI 0
#define OFF_ALO 65536
#define OFF_YS  131072
#define OFF_VFB 147456
#define OFF_RED 147968
#define SMEM_BYTES 148480

// row-major [row][256B-elem-row = 512B], XOR-swizzle to spread 16-lane column reads across banks
__device__ __forceinline__ unsigned swz(unsigned row, unsigned bytecol) {
    return row * 512u + (bytecol ^ ((row & 7u) << 4));
}

__global__ void lcde_init(const float* __restrict__ X, const float* __restrict__ IM,
                          const float* __restrict__ IB, float* __restrict__ yf0,
                          unsigned short* __restrict__ yb0)
{
    int b = blockIdx.x, h = threadIdx.x;
    const float* xr = X + (size_t)b * LL * DD;   // X[b,0,:]
    const float* m  = IM + h * DD;
    float s = IB[h];
    for (int d = 0; d < DD; ++d) s += xr[d] * m[d];
    yf0[b * HH + h] = s;
    yb0[b * HH + h] = f2bf(s);
}

__global__ void __launch_bounds__(256, 1)
lcde_main(const float* __restrict__ X, const float* __restrict__ vfA,
          const float* __restrict__ vfB,
          float* __restrict__ yf0, float* __restrict__ yf1,
          unsigned short* __restrict__ yb0, unsigned short* __restrict__ yb1,
          float* __restrict__ out)
{
    extern __shared__ char smem[];
    const int h = blockIdx.x;
    const int t = threadIdx.x;
    cg::grid_group grid = cg::this_grid();

    // ---- prologue: stage vf_A[h,:,:] into LDS as bf16 hi + bf16 residual, swizzled ----
    {
        const int o = t >> 1, kh = t & 1;
        const float* src = vfA + ((size_t)(h * OM + o)) * HH + kh * 128;
        for (int i0 = 0; i0 < 128; i0 += 8) {
            f32x4 a = *(const f32x4*)(src + i0);
            f32x4 b4 = *(const f32x4*)(src + i0 + 4);
            u16x8 hi, lo;
            for (int j = 0; j < 4; ++j) {
                float v = a[j];
                unsigned short hb = f2bf(v);
                hi[j] = hb; lo[j] = f2bf(v - bf2f(hb));
                v = b4[j];
                hb = f2bf(v);
                hi[4 + j] = hb; lo[4 + j] = f2bf(v - bf2f(hb));
            }
            unsigned bc = (unsigned)(kh * 256 + i0 * 2);
            *(u16x8*)(smem + OFF_AHI + swz(o, bc)) = hi;
            *(u16x8*)(smem + OFF_ALO + swz(o, bc)) = lo;
        }
        if (t < OM) ((float*)(smem + OFF_VFB))[t] = vfB[h * OM + t];
    }
    __syncthreads();

    const int w = t >> 6, lane = t & 63, g = lane >> 4, l15 = lane & 15;
    float* redp = (float*)(smem + OFF_RED);
    const float dt = 1.0f / 2048.0f;   // reference: dt = 1/length

    for (int n = 1; n <= NSTEP; ++n) {
        const float* ysrc          = (n & 1) ? yf0 : yf1;
        float* ydst                = (n & 1) ? yf1 : yf0;
        const unsigned short* ybs  = (n & 1) ? yb0 : yb1;
        unsigned short* ybd        = (n & 1) ? yb1 : yb0;

        __syncthreads();   // protect y_s / red reuse from previous step
        // stage y_{n-1} (bf16) -> LDS, swizzled
        {
            const int b = t >> 3, seg = t & 7;
            const u16x8* gp = (const u16x8*)(ybs + b * 256 + seg * 32);
            for (int q = 0; q < 4; ++q) {
                u16x8 v = gp[q];
                *(u16x8*)(smem + OFF_YS + swz((unsigned)b, (unsigned)(seg * 64 + q * 16))) = v;
            }
        }
        // load c values (global, L2-hot) early so latency hides under MFMA
        const float tn = (float)n * (float)(1.0 / 2047.0);   // ts = linspace(0,1,L)
        float cv[2][8];   // [nt][mt*4+j]
        float vb[8];
        for (int mt = 0; mt < 2; ++mt)
            for (int j = 0; j < 4; ++j) {
                int o = 16 * (2 * w + mt) + 4 * g + j;
                int idx = mt * 4 + j;
                vb[idx] = ((const float*)(smem + OFF_VFB))[o];
                for (int nt = 0; nt < 2; ++nt) {
                    int b = 16 * nt + l15;
                    cv[nt][idx] = (o == 0) ? tn
                        : X[((size_t)b * LL + n) * DD + (o - 1)];
                }
            }
        __syncthreads();   // y_s ready

        // u[o,b] = sum_k vfA[h,o,k] * y[b,k]  via MFMA (A = vfA slice, B = y^T)
        f32x4 acc[2][2] = {};
        for (int ks = 0; ks < 8; ++ks) {
            unsigned bc = 64u * ks + 16u * (unsigned)g;
            short8 a0h = *(const short8*)(smem + OFF_AHI + swz((unsigned)(16 * (2 * w) + l15), bc));
            short8 a0l = *(const short8*)(smem + OFF_ALO + swz((unsigned)(16 * (2 * w) + l15), bc));
            short8 a1h = *(const short8*)(smem + OFF_AHI + swz((unsigned)(16 * (2 * w + 1) + l15), bc));
            short8 a1l = *(const short8*)(smem + OFF_ALO + swz((unsigned)(16 * (2 * w + 1) + l15), bc));
            short8 b0  = *(const short8*)(smem + OFF_YS  + swz((unsigned)l15, bc));
            short8 b1  = *(const short8*)(smem + OFF_YS  + swz((unsigned)(16 + l15), bc));
            acc[0][0] = __builtin_amdgcn_mfma_f32_16x16x32_bf16(a0h, b0, acc[0][0], 0, 0, 0);
            acc[0][1] = __builtin_amdgcn_mfma_f32_16x16x32_bf16(a0h, b1, acc[0][1], 0, 0, 0);
            acc[1][0] = __builtin_amdgcn_mfma_f32_16x16x32_bf16(a1h, b0, acc[1][0], 0, 0, 0);
            acc[1][1] = __builtin_amdgcn_mfma_f32_16x16x32_bf16(a1h, b1, acc[1][1], 0, 0, 0);
            acc[0][0] = __builtin_amdgcn_mfma_f32_16x16x32_bf16(a0l, b0, acc[0][0], 0, 0, 0);
            acc[0][1] = __builtin_amdgcn_mfma_f32_16x16x32_bf16(a0l, b1, acc[0][1], 0, 0, 0);
            acc[1][0] = __builtin_amdgcn_mfma_f32_16x16x32_bf16(a1l, b0, acc[1][0], 0, 0, 0);
            acc[1][1] = __builtin_amdgcn_mfma_f32_16x16x32_bf16(a1l, b1, acc[1][1], 0, 0, 0);
        }

        // z[b] = sum_o c[b,o] * (u[o,b] + vfB[h,o])   (bias fused; each (b,o) counted once)
        float p0 = 0.f, p1 = 0.f;
        for (int mt = 0; mt < 2; ++mt)
            for (int j = 0; j < 4; ++j) {
                int idx = mt * 4 + j;
                p0 += cv[0][idx] * (acc[mt][0][j] + vb[idx]);
                p1 += cv[1][idx] * (acc[mt][1][j] + vb[idx]);
            }
        p0 += __shfl_xor(p0, 16, 64);
        p0 += __shfl_xor(p0, 32, 64);
        p1 += __shfl_xor(p1, 16, 64);
        p1 += __shfl_xor(p1, 32, 64);
        if (g == 0) {
            redp[w * 32 + 0 * 16 + l15] = p0;
            redp[w * 32 + 1 * 16 + l15] = p1;
        }
        __syncthreads();
        if (t < 32) {   // thread t = batch b
            float z = redp[t] + redp[32 + t] + redp[64 + t] + redp[96 + t];
            float yv = ysrc[t * HH + h] + dt * z;
            ydst[t * HH + h] = yv;
            ybd[t * HH + h] = f2bf(yv);
            if (n == NSTEP) out[t * HH + h] = yv;
        }
        grid.sync();
    }
}

extern "C" void kernel_launch(void* const* d_in, const int* in_sizes, int n_in,
                              void* d_out, int out_size, void* d_ws, size_t ws_size,
                              hipStream_t stream) {
    const float* X   = (const float*)d_in[0];
    const float* IM  = (const float*)d_in[1];
    const float* IB  = (const float*)d_in[2];
    const float* vfA = (const float*)d_in[3];
    const float* vfB = (const float*)d_in[4];
    float* out = (float*)d_out;

    char* ws = (char*)d_ws;
    float* yf0 = (float*)(ws);                       // 32*256*4 = 32768
    float* yf1 = (float*)(ws + 32768);
    unsigned short* yb0 = (unsigned short*)(ws + 65536);   // 16384
    unsigned short* yb1 = (unsigned short*)(ws + 81920);   // total 98304 B

    lcde_init<<<dim3(BB), dim3(HH), 0, stream>>>(X, IM, IB, yf0, yb0);

    hipFuncSetAttribute(reinterpret_cast<const void*>(lcde_main),
                        hipFuncAttributeMaxDynamicSharedMemorySize, SMEM_BYTES);
    void* args[] = { (void*)&X, (void*)&vfA, (void*)&vfB, (void*)&yf0, (void*)&yf1,
                     (void*)&yb0, (void*)&yb1, (void*)&out };
    hipLaunchCooperativeKernel(reinterpret_cast<const void*>(lcde_main),
                               dim3(HH), dim3(HH), args, SMEM_BYTES, stream);
}

// Round 5
// 22662.903 us; speedup vs baseline: 2.9337x; 2.9337x over previous
//
#include <hip/hip_runtime.h>
#include <hip/hip_bf16.h>

#define BB 32
#define LL 2048
#define DD 127
#define HH 256
#define OM 128
#define NSTEP 2047
#define SPIN_CAP (1 << 15)   // bounded spin: protocol bug -> wrong answer, not GPU wedge

typedef short short8 __attribute__((ext_vector_type(8)));
typedef unsigned short u16x8 __attribute__((ext_vector_type(8)));
typedef float f32x4 __attribute__((ext_vector_type(4)));

__device__ __forceinline__ unsigned short f2bf(float f) {
    union { float f; unsigned int u; } v; v.f = f;
    unsigned int u = v.u;
    return (unsigned short)((u + 0x7fffu + ((u >> 16) & 1u)) >> 16);
}
__device__ __forceinline__ float bf2f(unsigned short b) {
    union { float f; unsigned int u; } v; v.u = ((unsigned int)b) << 16;
    return v.f;
}

// LDS layout (bytes): A_hi[128][256]bf16 | A_lo[128][256]bf16 | y_s[32][256]bf16 | vfB[128]f32 | red[4][2][16]f32
#define OFF_AHI 0
#define OFF_ALO 65536
#define OFF_YS  131072
#define OFF_VFB 147456
#define OFF_RED 147968
#define SMEM_BYTES 148480

// row stride 512B, XOR-swizzle spreads 16-lane column reads across banks
__device__ __forceinline__ unsigned swz(unsigned row, unsigned bytecol) {
    return row * 512u + (bytecol ^ ((row & 7u) << 4));
}

// ws layout: slots[256] (64B stride) @0 | flag @16384 | yinit f32[256][32] @16448 |
// yb0 bf16[256][32] @49216 | yb1 @65600  (total 81984 B)
#define WS_SLOTS 0
#define WS_FLAG  16384
#define WS_YINIT 16448
#define WS_YB0   49216
#define WS_YB1   65600

__global__ void lcde_init(const float* __restrict__ X, const float* __restrict__ IM,
                          const float* __restrict__ IB, char* __restrict__ ws)
{
    int b = blockIdx.x, h = threadIdx.x;
    const float* xr = X + (size_t)b * LL * DD;   // X[b,0,:]
    const float* m  = IM + h * DD;
    float s = IB[h];
    for (int d = 0; d < DD; ++d) s += xr[d] * m[d];
    ((float*)(ws + WS_YINIT))[h * 32 + b] = s;                    // [k=h][b] f32
    ((unsigned short*)(ws + WS_YB0))[h * 32 + b] = f2bf(s);       // [k=h][b] bf16
    if (b == 0)                                                    // zero slots+flag (ws re-poisoned each launch)
        for (int i = h; i < 4112; i += 256) ((unsigned*)ws)[i] = 0u;
}

__global__ void __launch_bounds__(256, 1)
lcde_main(const float* __restrict__ X, const float* __restrict__ vfA,
          const float* __restrict__ vfB, char* __restrict__ ws,
          float* __restrict__ out)
{
    extern __shared__ char smem[];
    const int h = blockIdx.x;
    const int t = threadIdx.x;

    // ---- prologue: stage vf_A[h,:,:] into LDS as bf16 hi + bf16 residual, swizzled ----
    {
        const int o = t >> 1, kh = t & 1;
        const float* src = vfA + ((size_t)(h * OM + o)) * HH + kh * 128;
        for (int i0 = 0; i0 < 128; i0 += 8) {
            f32x4 a = *(const f32x4*)(src + i0);
            f32x4 b4 = *(const f32x4*)(src + i0 + 4);
            u16x8 hi, lo;
            for (int j = 0; j < 4; ++j) {
                float v = a[j];
                unsigned short hb = f2bf(v);
                hi[j] = hb; lo[j] = f2bf(v - bf2f(hb));
                v = b4[j];
                hb = f2bf(v);
                hi[4 + j] = hb; lo[4 + j] = f2bf(v - bf2f(hb));
            }
            unsigned bc = (unsigned)(kh * 256 + i0 * 2);
            *(u16x8*)(smem + OFF_AHI + swz(o, bc)) = hi;
            *(u16x8*)(smem + OFF_ALO + swz(o, bc)) = lo;
        }
        if (t < OM) ((float*)(smem + OFF_VFB))[t] = vfB[h * OM + t];
    }

    // f32 master state for this block's h-row lives in wave-0 registers: lane t<32 holds y[b=t][h]
    float y_reg = 0.f;
    if (t < 32) y_reg = ((const float*)(ws + WS_YINIT))[h * 32 + t];
    __syncthreads();

    unsigned* slots = (unsigned*)(ws + WS_SLOTS);          // 64B stride per block
    unsigned* flag  = (unsigned*)(ws + WS_FLAG);
    unsigned short* yb[2] = { (unsigned short*)(ws + WS_YB0), (unsigned short*)(ws + WS_YB1) };

    const int w = t >> 6, lane = t & 63, g = lane >> 4, l15 = lane & 15;
    float* redp = (float*)(smem + OFF_RED);
    const float dt = 1.0f / 2048.0f;   // reference: dt = 1/length

    for (int n = 1; n <= NSTEP; ++n) {
        const unsigned short* ysrc = yb[(n - 1) & 1];
        unsigned short* ydst       = yb[n & 1];
        const unsigned epoch = (unsigned)(n - 1);

        // c values (global X, L2/L3-hot) + vfB — independent of y, issued before the
        // barrier wait so their latency hides under the spin.
        const float tn = (float)n * (float)(1.0 / 2047.0);   // ts = linspace(0,1,L)
        float cv[2][8];   // [nt][mt*4+j]
        float vb[8];
        for (int mt = 0; mt < 2; ++mt)
            for (int j = 0; j < 4; ++j) {
                int o = 16 * (2 * w + mt) + 4 * g + j;
                int idx = mt * 4 + j;
                vb[idx] = ((const float*)(smem + OFF_VFB))[o];
                for (int nt = 0; nt < 2; ++nt) {
                    int b = 16 * nt + l15;
                    cv[nt][idx] = (o == 0) ? tn
                        : X[((size_t)b * LL + n) * DD + (o - 1)];
                }
            }

        // ---- leader (block 0): aggregate per-block arrival slots for epoch, publish flag ----
        if (h == 0) {
            int guard = 0;
            while (__hip_atomic_load(slots + t * 16, __ATOMIC_RELAXED, __HIP_MEMORY_SCOPE_AGENT) < epoch
                   && ++guard < SPIN_CAP)
                __builtin_amdgcn_s_sleep(1);
            __syncthreads();
            if (t == 0)
                __hip_atomic_store(flag, epoch, __ATOMIC_RELEASE, __HIP_MEMORY_SCOPE_AGENT);
        }
        // ---- all blocks: wait for epoch flag, then acquire-invalidate caches ----
        if (t == 0) {
            int guard = 0;
            while (__hip_atomic_load(flag, __ATOMIC_RELAXED, __HIP_MEMORY_SCOPE_AGENT) < epoch
                   && ++guard < SPIN_CAP)
                __builtin_amdgcn_s_sleep(1);
            __threadfence();   // acquire: L1/L2 invalidate so staged y reads see remote writes
        }
        __syncthreads();

        // ---- stage y_{n-1} (bf16, [k][b] global) -> LDS y_s[b][k], swizzled ----
        for (int i = 0; i < 4; ++i) {
            int k  = 64 * i + (t >> 2);
            int b0 = (t & 3) * 8;
            u16x8 v = *(const u16x8*)(ysrc + k * 32 + b0);
            for (int j = 0; j < 8; ++j)
                *(unsigned short*)(smem + OFF_YS + swz((unsigned)(b0 + j), (unsigned)(2 * k))) = v[j];
        }
        __syncthreads();

        // ---- u[o,b] = sum_k vfA[h,o,k] * y[b,k] via MFMA ----
        f32x4 acc[2][2] = {};
        for (int ks = 0; ks < 8; ++ks) {
            unsigned bc = 64u * ks + 16u * (unsigned)g;
            short8 a0h = *(const short8*)(smem + OFF_AHI + swz((unsigned)(16 * (2 * w) + l15), bc));
            short8 a0l = *(const short8*)(smem + OFF_ALO + swz((unsigned)(16 * (2 * w) + l15), bc));
            short8 a1h = *(const short8*)(smem + OFF_AHI + swz((unsigned)(16 * (2 * w + 1) + l15), bc));
            short8 a1l = *(const short8*)(smem + OFF_ALO + swz((unsigned)(16 * (2 * w + 1) + l15), bc));
            short8 b0  = *(const short8*)(smem + OFF_YS  + swz((unsigned)l15, bc));
            short8 b1  = *(const short8*)(smem + OFF_YS  + swz((unsigned)(16 + l15), bc));
            acc[0][0] = __builtin_amdgcn_mfma_f32_16x16x32_bf16(a0h, b0, acc[0][0], 0, 0, 0);
            acc[0][1] = __builtin_amdgcn_mfma_f32_16x16x32_bf16(a0h, b1, acc[0][1], 0, 0, 0);
            acc[1][0] = __builtin_amdgcn_mfma_f32_16x16x32_bf16(a1h, b0, acc[1][0], 0, 0, 0);
            acc[1][1] = __builtin_amdgcn_mfma_f32_16x16x32_bf16(a1h, b1, acc[1][1], 0, 0, 0);
            acc[0][0] = __builtin_amdgcn_mfma_f32_16x16x32_bf16(a0l, b0, acc[0][0], 0, 0, 0);
            acc[0][1] = __builtin_amdgcn_mfma_f32_16x16x32_bf16(a0l, b1, acc[0][1], 0, 0, 0);
            acc[1][0] = __builtin_amdgcn_mfma_f32_16x16x32_bf16(a1l, b0, acc[1][0], 0, 0, 0);
            acc[1][1] = __builtin_amdgcn_mfma_f32_16x16x32_bf16(a1l, b1, acc[1][1], 0, 0, 0);
        }

        // ---- z[b] = sum_o c[b,o] * (u[o,b] + vfB[h,o]) ----
        float p0 = 0.f, p1 = 0.f;
        for (int mt = 0; mt < 2; ++mt)
            for (int j = 0; j < 4; ++j) {
                int idx = mt * 4 + j;
                p0 += cv[0][idx] * (acc[mt][0][j] + vb[idx]);
                p1 += cv[1][idx] * (acc[mt][1][j] + vb[idx]);
            }
        p0 += __shfl_xor(p0, 16, 64);
        p0 += __shfl_xor(p0, 32, 64);
        p1 += __shfl_xor(p1, 16, 64);
        p1 += __shfl_xor(p1, 32, 64);
        if (g == 0) {
            redp[w * 32 + 0 * 16 + l15] = p0;
            redp[w * 32 + 1 * 16 + l15] = p1;
        }
        __syncthreads();

        // ---- tail: y update in registers; publish one coalesced 64B line ----
        if (t < 32) {
            float z = redp[t] + redp[32 + t] + redp[64 + t] + redp[96 + t];
            y_reg += dt * z;
            ydst[h * 32 + t] = f2bf(y_reg);
            if (n == NSTEP) out[t * HH + h] = y_reg;
        }
        // ---- arrive: release-store this block's slot (same wave as ydst stores -> ordered) ----
        if (t == 0)
            __hip_atomic_store(slots + h * 16, (unsigned)n, __ATOMIC_RELEASE, __HIP_MEMORY_SCOPE_AGENT);
    }
}

extern "C" void kernel_launch(void* const* d_in, const int* in_sizes, int n_in,
                              void* d_out, int out_size, void* d_ws, size_t ws_size,
                              hipStream_t stream) {
    const float* X   = (const float*)d_in[0];
    const float* IM  = (const float*)d_in[1];
    const float* IB  = (const float*)d_in[2];
    const float* vfA = (const float*)d_in[3];
    const float* vfB = (const float*)d_in[4];
    float* out = (float*)d_out;
    char* ws = (char*)d_ws;

    lcde_init<<<dim3(BB), dim3(HH), 0, stream>>>(X, IM, IB, ws);

    hipFuncSetAttribute(reinterpret_cast<const void*>(lcde_main),
                        hipFuncAttributeMaxDynamicSharedMemorySize, SMEM_BYTES);
    void* args[] = { (void*)&X, (void*)&vfA, (void*)&vfB, (void*)&ws, (void*)&out };
    hipLaunchCooperativeKernel(reinterpret_cast<const void*>(lcde_main),
                               dim3(HH), dim3(HH), args, SMEM_BYTES, stream);
}